// Round 17
// baseline (528.179 us; speedup 1.0000x reference)
//
#include <hip/hip_runtime.h>
#include <hip/hip_bf16.h>
#include <cstdint>
#include <cstddef>
#include <cmath>

#define NH 16
#define HD 64
#define SS 2048
#define DM 1024
#define MTOT 4096   // B*S

typedef __attribute__((ext_vector_type(8))) short short8;
typedef __attribute__((ext_vector_type(4))) float float4v;
typedef __attribute__((ext_vector_type(4))) int int4v;
typedef __attribute__((ext_vector_type(4))) unsigned short ushort4v;

__device__ __forceinline__ unsigned short f2bf(float f){
  unsigned int u = __builtin_bit_cast(unsigned int, f);
  u += 0x7FFFu + ((u >> 16) & 1u);   // RNE; inputs finite
  return (unsigned short)(u >> 16);
}

__device__ __forceinline__ void gload16(const void* g, void* l){
  __builtin_amdgcn_global_load_lds((const __attribute__((address_space(1))) void*)g,
                                   (__attribute__((address_space(3))) void*)l, 16, 0, 0);
}

// LDS-only barrier (no implicit vmcnt(0) drain; NT stores stay in flight)
__device__ __forceinline__ void soft_barrier(){
  asm volatile("s_waitcnt lgkmcnt(0)" ::: "memory");
  __builtin_amdgcn_s_barrier();
  __builtin_amdgcn_sched_barrier(0);
}

// ---------- f32 -> bf16 bulk convert, z-batched ----------
__global__ __launch_bounds__(256) void cvt3_kernel(
    const float* __restrict__ s0, const float* __restrict__ s1, const float* __restrict__ s2,
    unsigned short* __restrict__ d0, unsigned short* __restrict__ d1, unsigned short* __restrict__ d2,
    int n){
  const int z = blockIdx.z;
  const float* src = z==0 ? s0 : (z==1 ? s1 : s2);
  unsigned short* dst = z==0 ? d0 : (z==1 ? d1 : d2);
  for (int i = (blockIdx.x*blockDim.x + threadIdx.x)*4; i < n; i += gridDim.x*blockDim.x*4){
    float4v v = *reinterpret_cast<const float4v*>(src + i);
    ushort4v o;
    o.x = f2bf(v.x); o.y = f2bf(v.y); o.z = f2bf(v.z); o.w = f2bf(v.w);
    *reinterpret_cast<ushort4v*>(dst + i) = o;
  }
}

__global__ __launch_bounds__(256) void cvt4_kernel(
    const float* __restrict__ s0, const float* __restrict__ s1,
    const float* __restrict__ s2, const float* __restrict__ s3,
    unsigned short* __restrict__ d0, unsigned short* __restrict__ d1,
    unsigned short* __restrict__ d2, unsigned short* __restrict__ d3,
    int n){
  const int z = blockIdx.z;
  const float* src = z==0 ? s0 : (z==1 ? s1 : (z==2 ? s2 : s3));
  unsigned short* dst = z==0 ? d0 : (z==1 ? d1 : (z==2 ? d2 : d3));
  for (int i = (blockIdx.x*blockDim.x + threadIdx.x)*4; i < n; i += gridDim.x*blockDim.x*4){
    float4v v = *reinterpret_cast<const float4v*>(src + i);
    ushort4v o;
    o.x = f2bf(v.x); o.y = f2bf(v.y); o.z = f2bf(v.z); o.w = f2bf(v.w);
    *reinterpret_cast<ushort4v*>(dst + i) = o;
  }
}

// ---------- batched projection GEMM: z in {q,k,v}; z==2 writes V^T ----------
__global__ __launch_bounds__(256) void gemm_proj(
    const unsigned short* __restrict__ X0, const unsigned short* __restrict__ X1, const unsigned short* __restrict__ X2,
    const unsigned short* __restrict__ W0, const unsigned short* __restrict__ W1, const unsigned short* __restrict__ W2,
    const float* __restrict__ b0, const float* __restrict__ b1, const float* __restrict__ b2,
    unsigned short* __restrict__ O0, unsigned short* __restrict__ O1, unsigned short* __restrict__ O2){
  __shared__ unsigned short Alds[128*32];
  __shared__ unsigned short Blds[128*32];
  const int z = blockIdx.z;
  const unsigned short* A  = z==0 ? X0 : (z==1 ? X1 : X2);
  const unsigned short* Bw = z==0 ? W0 : (z==1 ? W1 : W2);
  const float* bias        = z==0 ? b0 : (z==1 ? b1 : b2);
  unsigned short* outp     = z==0 ? O0 : (z==1 ? O1 : O2);
  const bool vmode = (z == 2);
  const int K = DM;
  const int t = threadIdx.x;
  const int l = t & 63;
  const int w = t >> 6;
  const int m0 = blockIdx.y * 128, n0 = blockIdx.x * 128;
  const int wm = (w & 1)*64, wn = (w >> 1)*64;
  const int srow = t >> 2;
  const int scol = (t & 3)*8;
  const int lr = l & 15, lg = l >> 4;
  float4v acc[4][4] = {};
  for (int k0 = 0; k0 < K; k0 += 32){
    __syncthreads();
    gload16(A  + (size_t)(m0 + srow     )*K + k0 + scol, Alds + t*8);
    gload16(A  + (size_t)(m0 + srow + 64)*K + k0 + scol, Alds + 2048 + t*8);
    gload16(Bw + (size_t)(n0 + srow     )*K + k0 + scol, Blds + t*8);
    gload16(Bw + (size_t)(n0 + srow + 64)*K + k0 + scol, Blds + 2048 + t*8);
    asm volatile("s_waitcnt vmcnt(0)" ::: "memory");
    __syncthreads();
    short8 afrag[4], bfrag[4];
    #pragma unroll
    for (int mb = 0; mb < 4; ++mb)
      afrag[mb] = *reinterpret_cast<const short8*>(Alds + (wm + mb*16 + lr)*32 + lg*8);
    #pragma unroll
    for (int nb = 0; nb < 4; ++nb)
      bfrag[nb] = *reinterpret_cast<const short8*>(Blds + (wn + nb*16 + lr)*32 + lg*8);
    #pragma unroll
    for (int mb = 0; mb < 4; ++mb)
      #pragma unroll
      for (int nb = 0; nb < 4; ++nb)
        acc[mb][nb] = __builtin_amdgcn_mfma_f32_16x16x32_bf16(afrag[mb], bfrag[nb], acc[mb][nb], 0, 0, 0);
  }
  #pragma unroll
  for (int mb = 0; mb < 4; ++mb){
    #pragma unroll
    for (int nb = 0; nb < 4; ++nb){
      const int gn = n0 + wn + nb*16 + lr;
      const float biasv = bias[gn];
      #pragma unroll
      for (int r = 0; r < 4; ++r){
        const int gm = m0 + wm + mb*16 + lg*4 + r;
        float v = acc[mb][nb][r] + biasv;
        const int b_ = gm >> 11, s_ = gm & 2047, h_ = gn >> 6, d_ = gn & 63;
        if (!vmode)
          outp[((size_t)(b_*NH + h_)*SS + s_)*HD + d_] = f2bf(v);
        else
          outp[((size_t)(b_*NH + h_)*HD + d_)*SS + s_] = f2bf(v);
      }
    }
  }
}

// ---------- out-projection GEMM: f32 out, * stability ----------
__global__ __launch_bounds__(256) void gemm_out(const unsigned short* __restrict__ A,
                                                const unsigned short* __restrict__ Bw,
                                                const float* __restrict__ bias,
                                                float* __restrict__ outp,
                                                const float* __restrict__ oscale_p){
  __shared__ unsigned short Alds[128*32];
  __shared__ unsigned short Blds[128*32];
  const int K = DM, N = DM;
  const int t = threadIdx.x;
  const int l = t & 63;
  const int w = t >> 6;
  const int m0 = blockIdx.y * 128, n0 = blockIdx.x * 128;
  const int wm = (w & 1)*64, wn = (w >> 1)*64;
  const int srow = t >> 2;
  const int scol = (t & 3)*8;
  const int lr = l & 15, lg = l >> 4;
  float4v acc[4][4] = {};
  for (int k0 = 0; k0 < K; k0 += 32){
    __syncthreads();
    gload16(A  + (size_t)(m0 + srow     )*K + k0 + scol, Alds + t*8);
    gload16(A  + (size_t)(m0 + srow + 64)*K + k0 + scol, Alds + 2048 + t*8);
    gload16(Bw + (size_t)(n0 + srow     )*K + k0 + scol, Blds + t*8);
    gload16(Bw + (size_t)(n0 + srow + 64)*K + k0 + scol, Blds + 2048 + t*8);
    asm volatile("s_waitcnt vmcnt(0)" ::: "memory");
    __syncthreads();
    short8 afrag[4], bfrag[4];
    #pragma unroll
    for (int mb = 0; mb < 4; ++mb)
      afrag[mb] = *reinterpret_cast<const short8*>(Alds + (wm + mb*16 + lr)*32 + lg*8);
    #pragma unroll
    for (int nb = 0; nb < 4; ++nb)
      bfrag[nb] = *reinterpret_cast<const short8*>(Blds + (wn + nb*16 + lr)*32 + lg*8);
    #pragma unroll
    for (int mb = 0; mb < 4; ++mb)
      #pragma unroll
      for (int nb = 0; nb < 4; ++nb)
        acc[mb][nb] = __builtin_amdgcn_mfma_f32_16x16x32_bf16(afrag[mb], bfrag[nb], acc[mb][nb], 0, 0, 0);
  }
  const float osc = oscale_p[0];
  #pragma unroll
  for (int mb = 0; mb < 4; ++mb){
    #pragma unroll
    for (int nb = 0; nb < 4; ++nb){
      const int gn = n0 + wn + nb*16 + lr;
      const float biasv = bias[gn];
      #pragma unroll
      for (int r = 0; r < 4; ++r){
        const int gm = m0 + wm + mb*16 + lg*4 + r;
        outp[(size_t)gm*N + gn] = (acc[mb][nb][r] + biasv) * osc;
      }
    }
  }
}

// ---------- kernel A: stats + PV + AO (NO attnW stores) ----------
// bh-fastest (XCD-pinned K/V reads), occ 8 (no write stream to corrupt;
// 2x waves hide read latency). Writes cc = -log2(sum exp2) per row to
// stats for kernel B.
__global__ __launch_bounds__(256, 8) void attn_pv(
    const unsigned short* __restrict__ Qh,   // [B*H][S][64] bf16
    const unsigned short* __restrict__ Kh,   // [B*H][S][64] bf16
    const unsigned short* __restrict__ Vt,   // [B*H][64][S] bf16
    unsigned short* __restrict__ AO,         // [B][S][1024] bf16
    float* __restrict__ stats,               // [B*H][S] f32: cc per row
    const float* __restrict__ phase,
    const float* __restrict__ pc,
    const float* __restrict__ ascale)
{
  __shared__ float lred[4][32];
  __shared__ __attribute__((aligned(16))) float ored[4][32*32];

  const int t = threadIdx.x;
  const int w = t >> 6, l = t & 63;
  const int lr = l & 15, lg = l >> 4;
  const int bh = blockIdx.x, qt = blockIdx.y;
  const int b = bh >> 4, h = bh & 15;
  const int q0 = qt*32;
  const float scale2 = 0.125f * ascale[0] * (1.0f + pc[h] * sinf(phase[b]))
                       * 1.4426950408889634f;

  const unsigned short* qbase = Qh + ((size_t)bh*SS + q0 + lr)*HD + lg*8;
  short8 aq[2][2];
  aq[0][0] = *reinterpret_cast<const short8*>(qbase);
  aq[0][1] = *reinterpret_cast<const short8*>(qbase + 32);
  aq[1][0] = *reinterpret_cast<const short8*>(qbase + 16*HD);
  aq[1][1] = *reinterpret_cast<const short8*>(qbase + 16*HD + 32);

  const int tbase = w * 512;
  const unsigned short* kbase = Kh + ((size_t)bh*SS + tbase + lr)*HD + lg*8;

  // ---- pass 1: per-lane sum of exp2 per q-subtile
  float lsum[2] = {0.f, 0.f};
  #pragma unroll 2
  for (int tb = 0; tb < 32; ++tb){
    const unsigned short* kp = kbase + (size_t)tb*16*HD;
    short8 bk0 = *reinterpret_cast<const short8*>(kp);
    short8 bk1 = *reinterpret_cast<const short8*>(kp + 32);
    #pragma unroll
    for (int qs = 0; qs < 2; ++qs){
      float4v pacc = {};
      pacc = __builtin_amdgcn_mfma_f32_16x16x32_bf16(bk0, aq[qs][0], pacc, 0, 0, 0);
      pacc = __builtin_amdgcn_mfma_f32_16x16x32_bf16(bk1, aq[qs][1], pacc, 0, 0, 0);
      lsum[qs] += (exp2f(pacc[0]*scale2) + exp2f(pacc[1]*scale2))
                + (exp2f(pacc[2]*scale2) + exp2f(pacc[3]*scale2));
    }
  }
  #pragma unroll
  for (int mask = 16; mask < 64; mask <<= 1){
    lsum[0] += __shfl_xor(lsum[0], mask, 64);
    lsum[1] += __shfl_xor(lsum[1], mask, 64);
  }
  if (l < 16){
    lred[w][lr]    = lsum[0];
    lred[w][16+lr] = lsum[1];
  }
  __syncthreads();
  float cc[2];
  #pragma unroll
  for (int qs = 0; qs < 2; ++qs){
    const int row = qs*16 + lr;
    const float total = (lred[0][row] + lred[1][row]) + (lred[2][row] + lred[3][row]);
    cc[qs] = -__log2f(total);
  }
  if (w == 0 && l < 16){
    stats[(size_t)bh*SS + q0 + lr]      = cc[0];
    stats[(size_t)bh*SS + q0 + 16 + lr] = cc[1];
  }

  // ---- pass 2: recompute, exp2, bpermute -> PV only (no global stores)
  float4v oacc[2][4] = {};
  const unsigned short* vbase = Vt + ((size_t)bh*HD + lr)*SS + tbase + lg*8;
  const int idxA = (((lg & 1)*2)*16 + lr)*4;
  const int idxB = idxA + 64;
  const bool hi = (lg >= 2);

  for (int tp = 0; tp < 16; ++tp){
    const int tloc = tp*32;
    const unsigned short* kpA = kbase + (size_t)tloc*HD;
    short8 k0A = *reinterpret_cast<const short8*>(kpA);
    short8 k1A = *reinterpret_cast<const short8*>(kpA + 32);
    short8 k0B = *reinterpret_cast<const short8*>(kpA + 16*HD);
    short8 k1B = *reinterpret_cast<const short8*>(kpA + 16*HD + 32);
    short8 bv[4];
    #pragma unroll
    for (int dt = 0; dt < 4; ++dt)
      bv[dt] = *reinterpret_cast<const short8*>(vbase + (size_t)(dt*16)*SS + tloc);

    #pragma unroll
    for (int qs = 0; qs < 2; ++qs){
      float4v pA = {};
      pA = __builtin_amdgcn_mfma_f32_16x16x32_bf16(k0A, aq[qs][0], pA, 0, 0, 0);
      pA = __builtin_amdgcn_mfma_f32_16x16x32_bf16(k1A, aq[qs][1], pA, 0, 0, 0);
      float4v pB = {};
      pB = __builtin_amdgcn_mfma_f32_16x16x32_bf16(k0B, aq[qs][0], pB, 0, 0, 0);
      pB = __builtin_amdgcn_mfma_f32_16x16x32_bf16(k1B, aq[qs][1], pB, 0, 0, 0);
      float4v eA, eB;
      eA.x = exp2f(fmaf(pA[0], scale2, cc[qs]));
      eA.y = exp2f(fmaf(pA[1], scale2, cc[qs]));
      eA.z = exp2f(fmaf(pA[2], scale2, cc[qs]));
      eA.w = exp2f(fmaf(pA[3], scale2, cc[qs]));
      eB.x = exp2f(fmaf(pB[0], scale2, cc[qs]));
      eB.y = exp2f(fmaf(pB[1], scale2, cc[qs]));
      eB.z = exp2f(fmaf(pB[2], scale2, cc[qs]));
      eB.w = exp2f(fmaf(pB[3], scale2, cc[qs]));
      const int w0A = ((int)f2bf(eA.y) << 16) | (int)f2bf(eA.x);
      const int w1A = ((int)f2bf(eA.w) << 16) | (int)f2bf(eA.z);
      const int w0B = ((int)f2bf(eB.y) << 16) | (int)f2bf(eB.x);
      const int w1B = ((int)f2bf(eB.w) << 16) | (int)f2bf(eB.z);

      const int a0 = __builtin_amdgcn_ds_bpermute(idxA, w0A);
      const int b0 = __builtin_amdgcn_ds_bpermute(idxA, w0B);
      const int a1 = __builtin_amdgcn_ds_bpermute(idxA, w1A);
      const int b1 = __builtin_amdgcn_ds_bpermute(idxA, w1B);
      const int a2 = __builtin_amdgcn_ds_bpermute(idxB, w0A);
      const int b2 = __builtin_amdgcn_ds_bpermute(idxB, w0B);
      const int a3 = __builtin_amdgcn_ds_bpermute(idxB, w1A);
      const int b3 = __builtin_amdgcn_ds_bpermute(idxB, w1B);
      int4v words;
      words.x = hi ? b0 : a0;
      words.y = hi ? b1 : a1;
      words.z = hi ? b2 : a2;
      words.w = hi ? b3 : a3;
      const short8 pa = __builtin_bit_cast(short8, words);

      #pragma unroll
      for (int dt = 0; dt < 4; ++dt)
        oacc[qs][dt] = __builtin_amdgcn_mfma_f32_16x16x32_bf16(pa, bv[dt], oacc[qs][dt], 0, 0, 0);
    }
  }

  // ---- cross-wave O reduce in two 16-col chunks
  #pragma unroll
  for (int c = 0; c < 2; ++c){
    if (c) __syncthreads();
    #pragma unroll
    for (int qs = 0; qs < 2; ++qs)
      #pragma unroll
      for (int dl = 0; dl < 2; ++dl)
        #pragma unroll
        for (int r = 0; r < 4; ++r)
          ored[w][(qs*16 + lg*4 + r)*32 + dl*16 + lr] = oacc[qs][c*2 + dl][r];
    __syncthreads();
    const int row = t >> 3, c4 = (t & 7);
    const float4v* o0 = reinterpret_cast<const float4v*>(&ored[0][0]);
    const int fi = row*8 + c4;
    float4v s = o0[fi];
    s += o0[fi + 256];
    s += o0[fi + 512];
    s += o0[fi + 768];
    ushort4v o4;
    o4.x = f2bf(s.x); o4.y = f2bf(s.y); o4.z = f2bf(s.z); o4.w = f2bf(s.w);
    *reinterpret_cast<ushort4v*>(AO + ((size_t)b*SS + q0 + row)*DM + h*HD + c*32 + c4*4) = o4;
  }
}

// ---------- kernel B: attnW writer (near-pure write stream) ----------
// qt-fastest, occ 4 (the proven-clean write regime). Per 256-col chunk:
// 4 waves compute the 32x256 e-chunk (reads only L2/L3-hot K + Q), stage
// to LDS, then fill-style 1KB-contiguous NT stores. No PV, no V reads —
// the write stream competes with almost nothing.
__global__ __launch_bounds__(256, 4) void attnw_write(
    const unsigned short* __restrict__ Qh,   // [B*H][S][64] bf16
    const unsigned short* __restrict__ Kh,   // [B*H][S][64] bf16
    const float* __restrict__ stats,         // [B*H][S] f32 cc
    float* __restrict__ attnW,               // [B*H][S][S] f32
    const float* __restrict__ phase,
    const float* __restrict__ pc,
    const float* __restrict__ ascale)
{
  __shared__ __attribute__((aligned(16))) float smem[32*260];

  const int t = threadIdx.x;
  const int w = t >> 6, l = t & 63;
  const int lr = l & 15, lg = l >> 4;
  const int qt = blockIdx.x, bh = blockIdx.y;   // qt-FASTEST
  const int b = bh >> 4, h = bh & 15;
  const int q0 = qt*32;
  const float scale2 = 0.125f * ascale[0] * (1.0f + pc[h] * sinf(phase[b]))
                       * 1.4426950408889634f;

  const unsigned short* qbase = Qh + ((size_t)bh*SS + q0 + lr)*HD + lg*8;
  short8 aq[2][2];
  aq[0][0] = *reinterpret_cast<const short8*>(qbase);
  aq[0][1] = *reinterpret_cast<const short8*>(qbase + 32);
  aq[1][0] = *reinterpret_cast<const short8*>(qbase + 16*HD);
  aq[1][1] = *reinterpret_cast<const short8*>(qbase + 16*HD + 32);

  float cc[2];
  cc[0] = stats[(size_t)bh*SS + q0 + lr];
  cc[1] = stats[(size_t)bh*SS + q0 + 16 + lr];

  float* gwb = attnW + ((size_t)bh*SS + q0)*SS;
  const unsigned short* kb2 = Kh + ((size_t)bh*SS + lr)*HD + lg*8;

  for (int ch = 0; ch < 8; ++ch){
    #pragma unroll
    for (int sub = 0; sub < 2; ++sub){
      const int tloc = ch*256 + w*64 + sub*32;
      const unsigned short* kp = kb2 + (size_t)tloc*HD;
      short8 k0A = *reinterpret_cast<const short8*>(kp);
      short8 k1A = *reinterpret_cast<const short8*>(kp + 32);
      short8 k0B = *reinterpret_cast<const short8*>(kp + 16*HD);
      short8 k1B = *reinterpret_cast<const short8*>(kp + 16*HD + 32);
      #pragma unroll
      for (int qs = 0; qs < 2; ++qs){
        float4v pA = {};
        pA = __builtin_amdgcn_mfma_f32_16x16x32_bf16(k0A, aq[qs][0], pA, 0, 0, 0);
        pA = __builtin_amdgcn_mfma_f32_16x16x32_bf16(k1A, aq[qs][1], pA, 0, 0, 0);
        float4v pB = {};
        pB = __builtin_amdgcn_mfma_f32_16x16x32_bf16(k0B, aq[qs][0], pB, 0, 0, 0);
        pB = __builtin_amdgcn_mfma_f32_16x16x32_bf16(k1B, aq[qs][1], pB, 0, 0, 0);
        float4v eA, eB;
        eA.x = exp2f(fmaf(pA[0], scale2, cc[qs]));
        eA.y = exp2f(fmaf(pA[1], scale2, cc[qs]));
        eA.z = exp2f(fmaf(pA[2], scale2, cc[qs]));
        eA.w = exp2f(fmaf(pA[3], scale2, cc[qs]));
        eB.x = exp2f(fmaf(pB[0], scale2, cc[qs]));
        eB.y = exp2f(fmaf(pB[1], scale2, cc[qs]));
        eB.z = exp2f(fmaf(pB[2], scale2, cc[qs]));
        eB.w = exp2f(fmaf(pB[3], scale2, cc[qs]));
        const int cw = w*64 + sub*32;
        *reinterpret_cast<float4v*>(&smem[(qs*16 + lr)*260 + cw + lg*4]) = eA;
        *reinterpret_cast<float4v*>(&smem[(qs*16 + lr)*260 + cw + 16 + lg*4]) = eB;
      }
    }
    soft_barrier();
    // fill-style stores: wave w, iter i -> row i*4+w, 1KB contiguous, NT
    #pragma unroll
    for (int i = 0; i < 8; ++i){
      const int row = i*4 + w;
      const float4v val = *reinterpret_cast<const float4v*>(&smem[row*260 + l*4]);
      __builtin_nontemporal_store(val,
        reinterpret_cast<float4v*>(gwb + (size_t)row*SS + ch*256 + l*4));
    }
    soft_barrier();
  }
}

extern "C" void kernel_launch(void* const* d_in, const int* in_sizes, int n_in,
                              void* d_out, int out_size, void* d_ws, size_t ws_size,
                              hipStream_t stream){
  const float* q      = (const float*)d_in[0];
  const float* k      = (const float*)d_in[1];
  const float* v      = (const float*)d_in[2];
  const float* phase  = (const float*)d_in[3];
  const float* Wq     = (const float*)d_in[4];
  const float* bq     = (const float*)d_in[5];
  const float* Wk     = (const float*)d_in[6];
  const float* bk     = (const float*)d_in[7];
  const float* Wv     = (const float*)d_in[8];
  const float* bv     = (const float*)d_in[9];
  const float* Wo     = (const float*)d_in[10];
  const float* bo     = (const float*)d_in[11];
  const float* pc     = (const float*)d_in[12];
  const float* ascale = (const float*)d_in[13];
  const float* stab   = (const float*)d_in[14];

  unsigned short* Xq  = (unsigned short*)d_ws;
  unsigned short* Xk  = Xq  + 4194304;
  unsigned short* Xv  = Xk  + 4194304;
  unsigned short* Wqb = Xv  + 4194304;
  unsigned short* Wkb = Wqb + 1048576;
  unsigned short* Wvb = Wkb + 1048576;
  unsigned short* Wob = Wvb + 1048576;
  unsigned short* Qh  = Wob + 1048576;
  unsigned short* Kh  = Qh  + 4194304;
  unsigned short* Vt  = Kh  + 4194304;
  unsigned short* AO  = Vt  + 4194304;
  float* stats = (float*)(AO + 4194304);   // 64MB + 256KB of ws

  float* out0  = (float*)d_out;
  float* attnW = out0 + (size_t)MTOT*DM;

  cvt3_kernel<<<dim3(512,1,3), 256, 0, stream>>>(q, k, v, Xq, Xk, Xv, MTOT*DM);
  cvt4_kernel<<<dim3(128,1,4), 256, 0, stream>>>(Wq, Wk, Wv, Wo, Wqb, Wkb, Wvb, Wob, DM*DM);

  gemm_proj<<<dim3(DM/128, MTOT/128, 3), 256, 0, stream>>>(
      Xq, Xk, Xv, Wqb, Wkb, Wvb, bq, bk, bv, Qh, Kh, Vt);

  attn_pv<<<dim3(32, SS/32, 1), 256, 0, stream>>>(Qh, Kh, Vt, AO, stats,
                                                  phase, pc, ascale);

  attnw_write<<<dim3(SS/32, 32, 1), 256, 0, stream>>>(Qh, Kh, stats, attnW,
                                                      phase, pc, ascale);

  gemm_out<<<dim3(DM/128, MTOT/128, 1), 256, 0, stream>>>(AO, Wob, bo, out0, stab);
}

// Round 18
// 303.903 us; speedup vs baseline: 1.7380x; 1.7380x over previous
//
#include <hip/hip_runtime.h>
#include <hip/hip_bf16.h>
#include <cstdint>
#include <cstddef>
#include <cmath>

#define NH 16
#define HD 64
#define SS 2048
#define DM 1024
#define MTOT 4096   // B*S

typedef __attribute__((ext_vector_type(8))) short short8;
typedef __attribute__((ext_vector_type(4))) float float4v;
typedef __attribute__((ext_vector_type(4))) int int4v;
typedef __attribute__((ext_vector_type(4))) unsigned short ushort4v;

__device__ __forceinline__ unsigned short f2bf(float f){
  unsigned int u = __builtin_bit_cast(unsigned int, f);
  u += 0x7FFFu + ((u >> 16) & 1u);   // RNE; inputs finite
  return (unsigned short)(u >> 16);
}

__device__ __forceinline__ void gload16(const void* g, void* l){
  __builtin_amdgcn_global_load_lds((const __attribute__((address_space(1))) void*)g,
                                   (__attribute__((address_space(3))) void*)l, 16, 0, 0);
}

// LDS-only barrier (no implicit vmcnt(0) drain; NT stores stay in flight)
__device__ __forceinline__ void soft_barrier(){
  asm volatile("s_waitcnt lgkmcnt(0)" ::: "memory");
  __builtin_amdgcn_s_barrier();
  __builtin_amdgcn_sched_barrier(0);
}

// ---------- f32 -> bf16 bulk convert, z-batched ----------
__global__ __launch_bounds__(256) void cvt3_kernel(
    const float* __restrict__ s0, const float* __restrict__ s1, const float* __restrict__ s2,
    unsigned short* __restrict__ d0, unsigned short* __restrict__ d1, unsigned short* __restrict__ d2,
    int n){
  const int z = blockIdx.z;
  const float* src = z==0 ? s0 : (z==1 ? s1 : s2);
  unsigned short* dst = z==0 ? d0 : (z==1 ? d1 : d2);
  for (int i = (blockIdx.x*blockDim.x + threadIdx.x)*4; i < n; i += gridDim.x*blockDim.x*4){
    float4v v = *reinterpret_cast<const float4v*>(src + i);
    ushort4v o;
    o.x = f2bf(v.x); o.y = f2bf(v.y); o.z = f2bf(v.z); o.w = f2bf(v.w);
    *reinterpret_cast<ushort4v*>(dst + i) = o;
  }
}

__global__ __launch_bounds__(256) void cvt4_kernel(
    const float* __restrict__ s0, const float* __restrict__ s1,
    const float* __restrict__ s2, const float* __restrict__ s3,
    unsigned short* __restrict__ d0, unsigned short* __restrict__ d1,
    unsigned short* __restrict__ d2, unsigned short* __restrict__ d3,
    int n){
  const int z = blockIdx.z;
  const float* src = z==0 ? s0 : (z==1 ? s1 : (z==2 ? s2 : s3));
  unsigned short* dst = z==0 ? d0 : (z==1 ? d1 : (z==2 ? d2 : d3));
  for (int i = (blockIdx.x*blockDim.x + threadIdx.x)*4; i < n; i += gridDim.x*blockDim.x*4){
    float4v v = *reinterpret_cast<const float4v*>(src + i);
    ushort4v o;
    o.x = f2bf(v.x); o.y = f2bf(v.y); o.z = f2bf(v.z); o.w = f2bf(v.w);
    *reinterpret_cast<ushort4v*>(dst + i) = o;
  }
}

// ---------- batched projection GEMM: z in {q,k,v}; z==2 writes V^T ----------
__global__ __launch_bounds__(256) void gemm_proj(
    const unsigned short* __restrict__ X0, const unsigned short* __restrict__ X1, const unsigned short* __restrict__ X2,
    const unsigned short* __restrict__ W0, const unsigned short* __restrict__ W1, const unsigned short* __restrict__ W2,
    const float* __restrict__ b0, const float* __restrict__ b1, const float* __restrict__ b2,
    unsigned short* __restrict__ O0, unsigned short* __restrict__ O1, unsigned short* __restrict__ O2){
  __shared__ unsigned short Alds[128*32];
  __shared__ unsigned short Blds[128*32];
  const int z = blockIdx.z;
  const unsigned short* A  = z==0 ? X0 : (z==1 ? X1 : X2);
  const unsigned short* Bw = z==0 ? W0 : (z==1 ? W1 : W2);
  const float* bias        = z==0 ? b0 : (z==1 ? b1 : b2);
  unsigned short* outp     = z==0 ? O0 : (z==1 ? O1 : O2);
  const bool vmode = (z == 2);
  const int K = DM;
  const int t = threadIdx.x;
  const int l = t & 63;
  const int w = t >> 6;
  const int m0 = blockIdx.y * 128, n0 = blockIdx.x * 128;
  const int wm = (w & 1)*64, wn = (w >> 1)*64;
  const int srow = t >> 2;
  const int scol = (t & 3)*8;
  const int lr = l & 15, lg = l >> 4;
  float4v acc[4][4] = {};
  for (int k0 = 0; k0 < K; k0 += 32){
    __syncthreads();
    gload16(A  + (size_t)(m0 + srow     )*K + k0 + scol, Alds + t*8);
    gload16(A  + (size_t)(m0 + srow + 64)*K + k0 + scol, Alds + 2048 + t*8);
    gload16(Bw + (size_t)(n0 + srow     )*K + k0 + scol, Blds + t*8);
    gload16(Bw + (size_t)(n0 + srow + 64)*K + k0 + scol, Blds + 2048 + t*8);
    asm volatile("s_waitcnt vmcnt(0)" ::: "memory");
    __syncthreads();
    short8 afrag[4], bfrag[4];
    #pragma unroll
    for (int mb = 0; mb < 4; ++mb)
      afrag[mb] = *reinterpret_cast<const short8*>(Alds + (wm + mb*16 + lr)*32 + lg*8);
    #pragma unroll
    for (int nb = 0; nb < 4; ++nb)
      bfrag[nb] = *reinterpret_cast<const short8*>(Blds + (wn + nb*16 + lr)*32 + lg*8);
    #pragma unroll
    for (int mb = 0; mb < 4; ++mb)
      #pragma unroll
      for (int nb = 0; nb < 4; ++nb)
        acc[mb][nb] = __builtin_amdgcn_mfma_f32_16x16x32_bf16(afrag[mb], bfrag[nb], acc[mb][nb], 0, 0, 0);
  }
  #pragma unroll
  for (int mb = 0; mb < 4; ++mb){
    #pragma unroll
    for (int nb = 0; nb < 4; ++nb){
      const int gn = n0 + wn + nb*16 + lr;
      const float biasv = bias[gn];
      #pragma unroll
      for (int r = 0; r < 4; ++r){
        const int gm = m0 + wm + mb*16 + lg*4 + r;
        float v = acc[mb][nb][r] + biasv;
        const int b_ = gm >> 11, s_ = gm & 2047, h_ = gn >> 6, d_ = gn & 63;
        if (!vmode)
          outp[((size_t)(b_*NH + h_)*SS + s_)*HD + d_] = f2bf(v);
        else
          outp[((size_t)(b_*NH + h_)*HD + d_)*SS + s_] = f2bf(v);
      }
    }
  }
}

// ---------- out-projection GEMM: f32 out, * stability ----------
__global__ __launch_bounds__(256) void gemm_out(const unsigned short* __restrict__ A,
                                                const unsigned short* __restrict__ Bw,
                                                const float* __restrict__ bias,
                                                float* __restrict__ outp,
                                                const float* __restrict__ oscale_p){
  __shared__ unsigned short Alds[128*32];
  __shared__ unsigned short Blds[128*32];
  const int K = DM, N = DM;
  const int t = threadIdx.x;
  const int l = t & 63;
  const int w = t >> 6;
  const int m0 = blockIdx.y * 128, n0 = blockIdx.x * 128;
  const int wm = (w & 1)*64, wn = (w >> 1)*64;
  const int srow = t >> 2;
  const int scol = (t & 3)*8;
  const int lr = l & 15, lg = l >> 4;
  float4v acc[4][4] = {};
  for (int k0 = 0; k0 < K; k0 += 32){
    __syncthreads();
    gload16(A  + (size_t)(m0 + srow     )*K + k0 + scol, Alds + t*8);
    gload16(A  + (size_t)(m0 + srow + 64)*K + k0 + scol, Alds + 2048 + t*8);
    gload16(Bw + (size_t)(n0 + srow     )*K + k0 + scol, Blds + t*8);
    gload16(Bw + (size_t)(n0 + srow + 64)*K + k0 + scol, Blds + 2048 + t*8);
    asm volatile("s_waitcnt vmcnt(0)" ::: "memory");
    __syncthreads();
    short8 afrag[4], bfrag[4];
    #pragma unroll
    for (int mb = 0; mb < 4; ++mb)
      afrag[mb] = *reinterpret_cast<const short8*>(Alds + (wm + mb*16 + lr)*32 + lg*8);
    #pragma unroll
    for (int nb = 0; nb < 4; ++nb)
      bfrag[nb] = *reinterpret_cast<const short8*>(Blds + (wn + nb*16 + lr)*32 + lg*8);
    #pragma unroll
    for (int mb = 0; mb < 4; ++mb)
      #pragma unroll
      for (int nb = 0; nb < 4; ++nb)
        acc[mb][nb] = __builtin_amdgcn_mfma_f32_16x16x32_bf16(afrag[mb], bfrag[nb], acc[mb][nb], 0, 0, 0);
  }
  const float osc = oscale_p[0];
  #pragma unroll
  for (int mb = 0; mb < 4; ++mb){
    #pragma unroll
    for (int nb = 0; nb < 4; ++nb){
      const int gn = n0 + wn + nb*16 + lr;
      const float biasv = bias[gn];
      #pragma unroll
      for (int r = 0; r < 4; ++r){
        const int gm = m0 + wm + mb*16 + lg*4 + r;
        outp[(size_t)gm*N + gn] = (acc[mb][nb][r] + biasv) * osc;
      }
    }
  }
}

// ---------- kernel A: SINGLE-PASS stats + PV + AO (no attnW stores) -------
// bh-fastest (XCD-pinned K/V), occ 4 (launch_bounds(256,4): 128-reg budget,
// NO SPILL — r15/r17's occ-8 runs spilled at the 64-reg cap: VGPR_Count 32
// + ~650MB phantom scratch writes). Unnormalized-e trick: e=exp2(s*scale2)
// (bounded [1/4,4], no max needed), O = (sum e_bf16 * V) / (sum e); one QK
// pass instead of two. Writes cc=-log2(sum) to stats for attnw_write
// (identical cc arithmetic to r13: same per-lane accumulation order,
// same lg-shuffle + cross-wave LDS reduction).
__global__ __launch_bounds__(256, 4) void attn_pv(
    const unsigned short* __restrict__ Qh,   // [B*H][S][64] bf16
    const unsigned short* __restrict__ Kh,   // [B*H][S][64] bf16
    const unsigned short* __restrict__ Vt,   // [B*H][64][S] bf16
    unsigned short* __restrict__ AO,         // [B][S][1024] bf16
    float* __restrict__ stats,               // [B*H][S] f32: cc per row
    const float* __restrict__ phase,
    const float* __restrict__ pc,
    const float* __restrict__ ascale)
{
  __shared__ float lred[4][32];
  __shared__ __attribute__((aligned(16))) float ored[4][32*32];

  const int t = threadIdx.x;
  const int w = t >> 6, l = t & 63;
  const int lr = l & 15, lg = l >> 4;
  const int bh = blockIdx.x, qt = blockIdx.y;
  const int b = bh >> 4, h = bh & 15;
  const int q0 = qt*32;
  const float scale2 = 0.125f * ascale[0] * (1.0f + pc[h] * sinf(phase[b]))
                       * 1.4426950408889634f;

  const unsigned short* qbase = Qh + ((size_t)bh*SS + q0 + lr)*HD + lg*8;
  short8 aq[2][2];
  aq[0][0] = *reinterpret_cast<const short8*>(qbase);
  aq[0][1] = *reinterpret_cast<const short8*>(qbase + 32);
  aq[1][0] = *reinterpret_cast<const short8*>(qbase + 16*HD);
  aq[1][1] = *reinterpret_cast<const short8*>(qbase + 16*HD + 32);

  const int tbase = w * 512;
  const unsigned short* kbase = Kh + ((size_t)bh*SS + tbase + lr)*HD + lg*8;
  const unsigned short* vbase = Vt + ((size_t)bh*HD + lr)*SS + tbase + lg*8;
  const int idxA = (((lg & 1)*2)*16 + lr)*4;
  const int idxB = idxA + 64;
  const bool hi = (lg >= 2);

  float lsum[2] = {0.f, 0.f};
  float4v oacc[2][4] = {};

  // ---- single fused pass over this wave's 512 t-cols
  for (int tp = 0; tp < 16; ++tp){
    const int tloc = tp*32;
    const unsigned short* kpA = kbase + (size_t)tloc*HD;
    short8 k0A = *reinterpret_cast<const short8*>(kpA);
    short8 k1A = *reinterpret_cast<const short8*>(kpA + 32);
    short8 k0B = *reinterpret_cast<const short8*>(kpA + 16*HD);
    short8 k1B = *reinterpret_cast<const short8*>(kpA + 16*HD + 32);
    short8 bv[4];
    #pragma unroll
    for (int dt = 0; dt < 4; ++dt)
      bv[dt] = *reinterpret_cast<const short8*>(vbase + (size_t)(dt*16)*SS + tloc);

    #pragma unroll
    for (int qs = 0; qs < 2; ++qs){
      float4v pA = {};
      pA = __builtin_amdgcn_mfma_f32_16x16x32_bf16(k0A, aq[qs][0], pA, 0, 0, 0);
      pA = __builtin_amdgcn_mfma_f32_16x16x32_bf16(k1A, aq[qs][1], pA, 0, 0, 0);
      float4v pB = {};
      pB = __builtin_amdgcn_mfma_f32_16x16x32_bf16(k0B, aq[qs][0], pB, 0, 0, 0);
      pB = __builtin_amdgcn_mfma_f32_16x16x32_bf16(k1B, aq[qs][1], pB, 0, 0, 0);
      float4v eA, eB;
      eA.x = exp2f(pA[0]*scale2);
      eA.y = exp2f(pA[1]*scale2);
      eA.z = exp2f(pA[2]*scale2);
      eA.w = exp2f(pA[3]*scale2);
      eB.x = exp2f(pB[0]*scale2);
      eB.y = exp2f(pB[1]*scale2);
      eB.z = exp2f(pB[2]*scale2);
      eB.w = exp2f(pB[3]*scale2);
      lsum[qs] += ((eA.x + eA.y) + (eA.z + eA.w))
                + ((eB.x + eB.y) + (eB.z + eB.w));

      const int w0A = ((int)f2bf(eA.y) << 16) | (int)f2bf(eA.x);
      const int w1A = ((int)f2bf(eA.w) << 16) | (int)f2bf(eA.z);
      const int w0B = ((int)f2bf(eB.y) << 16) | (int)f2bf(eB.x);
      const int w1B = ((int)f2bf(eB.w) << 16) | (int)f2bf(eB.z);
      const int a0 = __builtin_amdgcn_ds_bpermute(idxA, w0A);
      const int b0 = __builtin_amdgcn_ds_bpermute(idxA, w0B);
      const int a1 = __builtin_amdgcn_ds_bpermute(idxA, w1A);
      const int b1 = __builtin_amdgcn_ds_bpermute(idxA, w1B);
      const int a2 = __builtin_amdgcn_ds_bpermute(idxB, w0A);
      const int b2 = __builtin_amdgcn_ds_bpermute(idxB, w0B);
      const int a3 = __builtin_amdgcn_ds_bpermute(idxB, w1A);
      const int b3 = __builtin_amdgcn_ds_bpermute(idxB, w1B);
      int4v words;
      words.x = hi ? b0 : a0;
      words.y = hi ? b1 : a1;
      words.z = hi ? b2 : a2;
      words.w = hi ? b3 : a3;
      const short8 pa = __builtin_bit_cast(short8, words);

      #pragma unroll
      for (int dt = 0; dt < 4; ++dt)
        oacc[qs][dt] = __builtin_amdgcn_mfma_f32_16x16x32_bf16(pa, bv[dt], oacc[qs][dt], 0, 0, 0);
    }
  }

  // ---- reduce sums: lg-shuffle (masks 16,32) then cross-wave via LDS
  #pragma unroll
  for (int mask = 16; mask < 64; mask <<= 1){
    lsum[0] += __shfl_xor(lsum[0], mask, 64);
    lsum[1] += __shfl_xor(lsum[1], mask, 64);
  }
  if (l < 16){
    lred[w][lr]    = lsum[0];
    lred[w][16+lr] = lsum[1];
  }
  __syncthreads();

  // per-lane inverse totals for the 4 q-rows this lane's oacc covers
  float rrl[2][4];
  #pragma unroll
  for (int qs = 0; qs < 2; ++qs)
    #pragma unroll
    for (int r = 0; r < 4; ++r){
      const int row = qs*16 + lg*4 + r;
      const float total = (lred[0][row] + lred[1][row]) + (lred[2][row] + lred[3][row]);
      rrl[qs][r] = 1.0f / total;
    }
  // stats for attnw_write: cc = -log2(total)
  if (w == 0 && l < 16){
    const float t0 = (lred[0][lr]    + lred[1][lr])    + (lred[2][lr]    + lred[3][lr]);
    const float t1 = (lred[0][16+lr] + lred[1][16+lr]) + (lred[2][16+lr] + lred[3][16+lr]);
    stats[(size_t)bh*SS + q0 + lr]      = -__log2f(t0);
    stats[(size_t)bh*SS + q0 + 16 + lr] = -__log2f(t1);
  }
  // normalize O
  #pragma unroll
  for (int qs = 0; qs < 2; ++qs)
    #pragma unroll
    for (int dt = 0; dt < 4; ++dt)
      #pragma unroll
      for (int r = 0; r < 4; ++r)
        oacc[qs][dt][r] *= rrl[qs][r];

  // ---- cross-wave O reduce in two 16-col chunks
  #pragma unroll
  for (int c = 0; c < 2; ++c){
    if (c) __syncthreads();
    #pragma unroll
    for (int qs = 0; qs < 2; ++qs)
      #pragma unroll
      for (int dl = 0; dl < 2; ++dl)
        #pragma unroll
        for (int r = 0; r < 4; ++r)
          ored[w][(qs*16 + lg*4 + r)*32 + dl*16 + lr] = oacc[qs][c*2 + dl][r];
    __syncthreads();
    const int row = t >> 3, c4 = (t & 7);
    const float4v* o0 = reinterpret_cast<const float4v*>(&ored[0][0]);
    const int fi = row*8 + c4;
    float4v s = o0[fi];
    s += o0[fi + 256];
    s += o0[fi + 512];
    s += o0[fi + 768];
    ushort4v o4;
    o4.x = f2bf(s.x); o4.y = f2bf(s.y); o4.z = f2bf(s.z); o4.w = f2bf(s.w);
    *reinterpret_cast<ushort4v*>(AO + ((size_t)b*SS + q0 + row)*DM + h*HD + c*32 + c4*4) = o4;
  }
}

// ---------- kernel B: attnW writer (near-pure write stream, ~98us r17) ----
__global__ __launch_bounds__(256, 4) void attnw_write(
    const unsigned short* __restrict__ Qh,   // [B*H][S][64] bf16
    const unsigned short* __restrict__ Kh,   // [B*H][S][64] bf16
    const float* __restrict__ stats,         // [B*H][S] f32 cc
    float* __restrict__ attnW,               // [B*H][S][S] f32
    const float* __restrict__ phase,
    const float* __restrict__ pc,
    const float* __restrict__ ascale)
{
  __shared__ __attribute__((aligned(16))) float smem[32*260];

  const int t = threadIdx.x;
  const int w = t >> 6, l = t & 63;
  const int lr = l & 15, lg = l >> 4;
  const int qt = blockIdx.x, bh = blockIdx.y;   // qt-FASTEST
  const int b = bh >> 4, h = bh & 15;
  const int q0 = qt*32;
  const float scale2 = 0.125f * ascale[0] * (1.0f + pc[h] * sinf(phase[b]))
                       * 1.4426950408889634f;

  const unsigned short* qbase = Qh + ((size_t)bh*SS + q0 + lr)*HD + lg*8;
  short8 aq[2][2];
  aq[0][0] = *reinterpret_cast<const short8*>(qbase);
  aq[0][1] = *reinterpret_cast<const short8*>(qbase + 32);
  aq[1][0] = *reinterpret_cast<const short8*>(qbase + 16*HD);
  aq[1][1] = *reinterpret_cast<const short8*>(qbase + 16*HD + 32);

  float cc[2];
  cc[0] = stats[(size_t)bh*SS + q0 + lr];
  cc[1] = stats[(size_t)bh*SS + q0 + 16 + lr];

  float* gwb = attnW + ((size_t)bh*SS + q0)*SS;
  const unsigned short* kb2 = Kh + ((size_t)bh*SS + lr)*HD + lg*8;

  for (int ch = 0; ch < 8; ++ch){
    #pragma unroll
    for (int sub = 0; sub < 2; ++sub){
      const int tloc = ch*256 + w*64 + sub*32;
      const unsigned short* kp = kb2 + (size_t)tloc*HD;
      short8 k0A = *reinterpret_cast<const short8*>(kp);
      short8 k1A = *reinterpret_cast<const short8*>(kp + 32);
      short8 k0B = *reinterpret_cast<const short8*>(kp + 16*HD);
      short8 k1B = *reinterpret_cast<const short8*>(kp + 16*HD + 32);
      #pragma unroll
      for (int qs = 0; qs < 2; ++qs){
        float4v pA = {};
        pA = __builtin_amdgcn_mfma_f32_16x16x32_bf16(k0A, aq[qs][0], pA, 0, 0, 0);
        pA = __builtin_amdgcn_mfma_f32_16x16x32_bf16(k1A, aq[qs][1], pA, 0, 0, 0);
        float4v pB = {};
        pB = __builtin_amdgcn_mfma_f32_16x16x32_bf16(k0B, aq[qs][0], pB, 0, 0, 0);
        pB = __builtin_amdgcn_mfma_f32_16x16x32_bf16(k1B, aq[qs][1], pB, 0, 0, 0);
        float4v eA, eB;
        eA.x = exp2f(fmaf(pA[0], scale2, cc[qs]));
        eA.y = exp2f(fmaf(pA[1], scale2, cc[qs]));
        eA.z = exp2f(fmaf(pA[2], scale2, cc[qs]));
        eA.w = exp2f(fmaf(pA[3], scale2, cc[qs]));
        eB.x = exp2f(fmaf(pB[0], scale2, cc[qs]));
        eB.y = exp2f(fmaf(pB[1], scale2, cc[qs]));
        eB.z = exp2f(fmaf(pB[2], scale2, cc[qs]));
        eB.w = exp2f(fmaf(pB[3], scale2, cc[qs]));
        const int cw = w*64 + sub*32;
        *reinterpret_cast<float4v*>(&smem[(qs*16 + lr)*260 + cw + lg*4]) = eA;
        *reinterpret_cast<float4v*>(&smem[(qs*16 + lr)*260 + cw + 16 + lg*4]) = eB;
      }
    }
    soft_barrier();
    // fill-style stores: wave w, iter i -> row i*4+w, 1KB contiguous, NT
    #pragma unroll
    for (int i = 0; i < 8; ++i){
      const int row = i*4 + w;
      const float4v val = *reinterpret_cast<const float4v*>(&smem[row*260 + l*4]);
      __builtin_nontemporal_store(val,
        reinterpret_cast<float4v*>(gwb + (size_t)row*SS + ch*256 + l*4));
    }
    soft_barrier();
  }
}

extern "C" void kernel_launch(void* const* d_in, const int* in_sizes, int n_in,
                              void* d_out, int out_size, void* d_ws, size_t ws_size,
                              hipStream_t stream){
  const float* q      = (const float*)d_in[0];
  const float* k      = (const float*)d_in[1];
  const float* v      = (const float*)d_in[2];
  const float* phase  = (const float*)d_in[3];
  const float* Wq     = (const float*)d_in[4];
  const float* bq     = (const float*)d_in[5];
  const float* Wk     = (const float*)d_in[6];
  const float* bk     = (const float*)d_in[7];
  const float* Wv     = (const float*)d_in[8];
  const float* bv     = (const float*)d_in[9];
  const float* Wo     = (const float*)d_in[10];
  const float* bo     = (const float*)d_in[11];
  const float* pc     = (const float*)d_in[12];
  const float* ascale = (const float*)d_in[13];
  const float* stab   = (const float*)d_in[14];

  unsigned short* Xq  = (unsigned short*)d_ws;
  unsigned short* Xk  = Xq  + 4194304;
  unsigned short* Xv  = Xk  + 4194304;
  unsigned short* Wqb = Xv  + 4194304;
  unsigned short* Wkb = Wqb + 1048576;
  unsigned short* Wvb = Wkb + 1048576;
  unsigned short* Wob = Wvb + 1048576;
  unsigned short* Qh  = Wob + 1048576;
  unsigned short* Kh  = Qh  + 4194304;
  unsigned short* Vt  = Kh  + 4194304;
  unsigned short* AO  = Vt  + 4194304;
  float* stats = (float*)(AO + 4194304);   // 64MB + 256KB of ws

  float* out0  = (float*)d_out;
  float* attnW = out0 + (size_t)MTOT*DM;

  cvt3_kernel<<<dim3(512,1,3), 256, 0, stream>>>(q, k, v, Xq, Xk, Xv, MTOT*DM);
  cvt4_kernel<<<dim3(128,1,4), 256, 0, stream>>>(Wq, Wk, Wv, Wo, Wqb, Wkb, Wvb, Wob, DM*DM);

  gemm_proj<<<dim3(DM/128, MTOT/128, 3), 256, 0, stream>>>(
      Xq, Xk, Xv, Wqb, Wkb, Wvb, bq, bk, bv, Qh, Kh, Vt);

  attn_pv<<<dim3(32, SS/32, 1), 256, 0, stream>>>(Qh, Kh, Vt, AO, stats,
                                                  phase, pc, ascale);

  attnw_write<<<dim3(SS/32, 32, 1), 256, 0, stream>>>(Qh, Kh, stats, attnW,
                                                      phase, pc, ascale);

  gemm_out<<<dim3(DM/128, MTOT/128, 1), 256, 0, stream>>>(AO, Wob, bo, out0, stab);
}

// Round 19
// 288.586 us; speedup vs baseline: 1.8302x; 1.0531x over previous
//
#include <hip/hip_runtime.h>
#include <hip/hip_bf16.h>
#include <cstdint>
#include <cstddef>
#include <cmath>

#define NH 16
#define HD 64
#define SS 2048
#define DM 1024
#define MTOT 4096   // B*S

typedef __attribute__((ext_vector_type(8))) short short8;
typedef __attribute__((ext_vector_type(4))) float float4v;
typedef __attribute__((ext_vector_type(4))) int int4v;
typedef __attribute__((ext_vector_type(4))) unsigned short ushort4v;

__device__ __forceinline__ unsigned short f2bf(float f){
  unsigned int u = __builtin_bit_cast(unsigned int, f);
  u += 0x7FFFu + ((u >> 16) & 1u);   // RNE; inputs finite
  return (unsigned short)(u >> 16);
}

__device__ __forceinline__ void gload16(const void* g, void* l){
  __builtin_amdgcn_global_load_lds((const __attribute__((address_space(1))) void*)g,
                                   (__attribute__((address_space(3))) void*)l, 16, 0, 0);
}

// ---------- f32 -> bf16 bulk convert, z-batched ----------
__global__ __launch_bounds__(256) void cvt3_kernel(
    const float* __restrict__ s0, const float* __restrict__ s1, const float* __restrict__ s2,
    unsigned short* __restrict__ d0, unsigned short* __restrict__ d1, unsigned short* __restrict__ d2,
    int n){
  const int z = blockIdx.z;
  const float* src = z==0 ? s0 : (z==1 ? s1 : s2);
  unsigned short* dst = z==0 ? d0 : (z==1 ? d1 : d2);
  for (int i = (blockIdx.x*blockDim.x + threadIdx.x)*4; i < n; i += gridDim.x*blockDim.x*4){
    float4v v = *reinterpret_cast<const float4v*>(src + i);
    ushort4v o;
    o.x = f2bf(v.x); o.y = f2bf(v.y); o.z = f2bf(v.z); o.w = f2bf(v.w);
    *reinterpret_cast<ushort4v*>(dst + i) = o;
  }
}

__global__ __launch_bounds__(256) void cvt4_kernel(
    const float* __restrict__ s0, const float* __restrict__ s1,
    const float* __restrict__ s2, const float* __restrict__ s3,
    unsigned short* __restrict__ d0, unsigned short* __restrict__ d1,
    unsigned short* __restrict__ d2, unsigned short* __restrict__ d3,
    int n){
  const int z = blockIdx.z;
  const float* src = z==0 ? s0 : (z==1 ? s1 : (z==2 ? s2 : s3));
  unsigned short* dst = z==0 ? d0 : (z==1 ? d1 : (z==2 ? d2 : d3));
  for (int i = (blockIdx.x*blockDim.x + threadIdx.x)*4; i < n; i += gridDim.x*blockDim.x*4){
    float4v v = *reinterpret_cast<const float4v*>(src + i);
    ushort4v o;
    o.x = f2bf(v.x); o.y = f2bf(v.y); o.z = f2bf(v.z); o.w = f2bf(v.w);
    *reinterpret_cast<ushort4v*>(dst + i) = o;
  }
}

// ---------- batched projection GEMM: z in {q,k,v}; z==2 writes V^T ----------
__global__ __launch_bounds__(256) void gemm_proj(
    const unsigned short* __restrict__ X0, const unsigned short* __restrict__ X1, const unsigned short* __restrict__ X2,
    const unsigned short* __restrict__ W0, const unsigned short* __restrict__ W1, const unsigned short* __restrict__ W2,
    const float* __restrict__ b0, const float* __restrict__ b1, const float* __restrict__ b2,
    unsigned short* __restrict__ O0, unsigned short* __restrict__ O1, unsigned short* __restrict__ O2){
  __shared__ unsigned short Alds[128*32];
  __shared__ unsigned short Blds[128*32];
  const int z = blockIdx.z;
  const unsigned short* A  = z==0 ? X0 : (z==1 ? X1 : X2);
  const unsigned short* Bw = z==0 ? W0 : (z==1 ? W1 : W2);
  const float* bias        = z==0 ? b0 : (z==1 ? b1 : b2);
  unsigned short* outp     = z==0 ? O0 : (z==1 ? O1 : O2);
  const bool vmode = (z == 2);
  const int K = DM;
  const int t = threadIdx.x;
  const int l = t & 63;
  const int w = t >> 6;
  const int m0 = blockIdx.y * 128, n0 = blockIdx.x * 128;
  const int wm = (w & 1)*64, wn = (w >> 1)*64;
  const int srow = t >> 2;
  const int scol = (t & 3)*8;
  const int lr = l & 15, lg = l >> 4;
  float4v acc[4][4] = {};
  for (int k0 = 0; k0 < K; k0 += 32){
    __syncthreads();
    gload16(A  + (size_t)(m0 + srow     )*K + k0 + scol, Alds + t*8);
    gload16(A  + (size_t)(m0 + srow + 64)*K + k0 + scol, Alds + 2048 + t*8);
    gload16(Bw + (size_t)(n0 + srow     )*K + k0 + scol, Blds + t*8);
    gload16(Bw + (size_t)(n0 + srow + 64)*K + k0 + scol, Blds + 2048 + t*8);
    asm volatile("s_waitcnt vmcnt(0)" ::: "memory");
    __syncthreads();
    short8 afrag[4], bfrag[4];
    #pragma unroll
    for (int mb = 0; mb < 4; ++mb)
      afrag[mb] = *reinterpret_cast<const short8*>(Alds + (wm + mb*16 + lr)*32 + lg*8);
    #pragma unroll
    for (int nb = 0; nb < 4; ++nb)
      bfrag[nb] = *reinterpret_cast<const short8*>(Blds + (wn + nb*16 + lr)*32 + lg*8);
    #pragma unroll
    for (int mb = 0; mb < 4; ++mb)
      #pragma unroll
      for (int nb = 0; nb < 4; ++nb)
        acc[mb][nb] = __builtin_amdgcn_mfma_f32_16x16x32_bf16(afrag[mb], bfrag[nb], acc[mb][nb], 0, 0, 0);
  }
  #pragma unroll
  for (int mb = 0; mb < 4; ++mb){
    #pragma unroll
    for (int nb = 0; nb < 4; ++nb){
      const int gn = n0 + wn + nb*16 + lr;
      const float biasv = bias[gn];
      #pragma unroll
      for (int r = 0; r < 4; ++r){
        const int gm = m0 + wm + mb*16 + lg*4 + r;
        float v = acc[mb][nb][r] + biasv;
        const int b_ = gm >> 11, s_ = gm & 2047, h_ = gn >> 6, d_ = gn & 63;
        if (!vmode)
          outp[((size_t)(b_*NH + h_)*SS + s_)*HD + d_] = f2bf(v);
        else
          outp[((size_t)(b_*NH + h_)*HD + d_)*SS + s_] = f2bf(v);
      }
    }
  }
}

// ---------- out-projection GEMM: f32 out, * stability ----------
__global__ __launch_bounds__(256) void gemm_out(const unsigned short* __restrict__ A,
                                                const unsigned short* __restrict__ Bw,
                                                const float* __restrict__ bias,
                                                float* __restrict__ outp,
                                                const float* __restrict__ oscale_p){
  __shared__ unsigned short Alds[128*32];
  __shared__ unsigned short Blds[128*32];
  const int K = DM, N = DM;
  const int t = threadIdx.x;
  const int l = t & 63;
  const int w = t >> 6;
  const int m0 = blockIdx.y * 128, n0 = blockIdx.x * 128;
  const int wm = (w & 1)*64, wn = (w >> 1)*64;
  const int srow = t >> 2;
  const int scol = (t & 3)*8;
  const int lr = l & 15, lg = l >> 4;
  float4v acc[4][4] = {};
  for (int k0 = 0; k0 < K; k0 += 32){
    __syncthreads();
    gload16(A  + (size_t)(m0 + srow     )*K + k0 + scol, Alds + t*8);
    gload16(A  + (size_t)(m0 + srow + 64)*K + k0 + scol, Alds + 2048 + t*8);
    gload16(Bw + (size_t)(n0 + srow     )*K + k0 + scol, Blds + t*8);
    gload16(Bw + (size_t)(n0 + srow + 64)*K + k0 + scol, Blds + 2048 + t*8);
    asm volatile("s_waitcnt vmcnt(0)" ::: "memory");
    __syncthreads();
    short8 afrag[4], bfrag[4];
    #pragma unroll
    for (int mb = 0; mb < 4; ++mb)
      afrag[mb] = *reinterpret_cast<const short8*>(Alds + (wm + mb*16 + lr)*32 + lg*8);
    #pragma unroll
    for (int nb = 0; nb < 4; ++nb)
      bfrag[nb] = *reinterpret_cast<const short8*>(Blds + (wn + nb*16 + lr)*32 + lg*8);
    #pragma unroll
    for (int mb = 0; mb < 4; ++mb)
      #pragma unroll
      for (int nb = 0; nb < 4; ++nb)
        acc[mb][nb] = __builtin_amdgcn_mfma_f32_16x16x32_bf16(afrag[mb], bfrag[nb], acc[mb][nb], 0, 0, 0);
  }
  const float osc = oscale_p[0];
  #pragma unroll
  for (int mb = 0; mb < 4; ++mb){
    #pragma unroll
    for (int nb = 0; nb < 4; ++nb){
      const int gn = n0 + wn + nb*16 + lr;
      const float biasv = bias[gn];
      #pragma unroll
      for (int r = 0; r < 4; ++r){
        const int gm = m0 + wm + mb*16 + lg*4 + r;
        outp[(size_t)gm*N + gn] = (acc[mb][nb][r] + biasv) * osc;
      }
    }
  }
}

// ---------- fused attention: block-cooperative chunk staging (r11 best) ----
// Grid: (bh=32, qt=64); blockIdx.x=bh -> XCD-pinned K/V. Pass 2: 256-col
// chunks; 4 waves compute a 32x256 P-chunk, stage into shared [32][260],
// barrier, then NT stores with each instruction = 64 lanes x 16B = 1KB
// contiguous. occ 4 (higher spills/degrades). No-max exp2 softmax.
__global__ __launch_bounds__(256, 4) void attn_kernel(
    const unsigned short* __restrict__ Qh,   // [B*H][S][64] bf16
    const unsigned short* __restrict__ Kh,   // [B*H][S][64] bf16
    const unsigned short* __restrict__ Vt,   // [B*H][64][S] bf16
    unsigned short* __restrict__ AO,         // [B][S][1024] bf16
    float* __restrict__ attnW,               // [B*H][S][S] f32
    const float* __restrict__ phase,         // [B]
    const float* __restrict__ pc,            // [16]
    const float* __restrict__ ascale)        // [1]
{
  __shared__ float lred[4][32];
  __shared__ __attribute__((aligned(16))) float smem[32*260]; // stage; reused as ored

  const int t = threadIdx.x;
  const int w = t >> 6, l = t & 63;
  const int lr = l & 15, lg = l >> 4;
  const int bh = blockIdx.x, qt = blockIdx.y;
  const int b = bh >> 4, h = bh & 15;
  const int q0 = qt*32;
  const float scale2 = 0.125f * ascale[0] * (1.0f + pc[h] * sinf(phase[b]))
                       * 1.4426950408889634f;   // exp2 domain

  const unsigned short* qbase = Qh + ((size_t)bh*SS + q0 + lr)*HD + lg*8;
  short8 aq[2][2];
  aq[0][0] = *reinterpret_cast<const short8*>(qbase);
  aq[0][1] = *reinterpret_cast<const short8*>(qbase + 32);
  aq[1][0] = *reinterpret_cast<const short8*>(qbase + 16*HD);
  aq[1][1] = *reinterpret_cast<const short8*>(qbase + 16*HD + 32);

  // ---- pass 1: per-lane sum of exp2 per q-subtile (no max)
  const unsigned short* kbase1 = Kh + ((size_t)bh*SS + w*512 + lr)*HD + lg*8;
  float lsum[2] = {0.f, 0.f};
  #pragma unroll 2
  for (int tb = 0; tb < 32; ++tb){
    const unsigned short* kp = kbase1 + (size_t)tb*16*HD;
    short8 bk0 = *reinterpret_cast<const short8*>(kp);
    short8 bk1 = *reinterpret_cast<const short8*>(kp + 32);
    #pragma unroll
    for (int qs = 0; qs < 2; ++qs){
      float4v pacc = {};
      pacc = __builtin_amdgcn_mfma_f32_16x16x32_bf16(bk0, aq[qs][0], pacc, 0, 0, 0);
      pacc = __builtin_amdgcn_mfma_f32_16x16x32_bf16(bk1, aq[qs][1], pacc, 0, 0, 0);
      lsum[qs] += (exp2f(pacc[0]*scale2) + exp2f(pacc[1]*scale2))
                + (exp2f(pacc[2]*scale2) + exp2f(pacc[3]*scale2));
    }
  }
  #pragma unroll
  for (int mask = 16; mask < 64; mask <<= 1){
    lsum[0] += __shfl_xor(lsum[0], mask, 64);
    lsum[1] += __shfl_xor(lsum[1], mask, 64);
  }
  if (l < 16){
    lred[w][lr]    = lsum[0];
    lred[w][16+lr] = lsum[1];
  }
  __syncthreads();
  float cc[2];
  #pragma unroll
  for (int qs = 0; qs < 2; ++qs){
    const int row = qs*16 + lr;
    const float total = (lred[0][row] + lred[1][row]) + (lred[2][row] + lred[3][row]);
    cc[qs] = -__log2f(total);
  }

  // ---- pass 2: per 256-col chunk: compute+stage -> barrier -> 1KB stores
  float4v oacc[2][4] = {};
  float* gwb = attnW + ((size_t)bh*SS + q0)*SS;   // block's contiguous 256KB
  const unsigned short* kb2 = Kh + ((size_t)bh*SS + lr)*HD + lg*8;
  const unsigned short* vb2 = Vt + ((size_t)bh*HD + lr)*SS + lg*8;
  const int idxA = (((lg & 1)*2)*16 + lr)*4;
  const int idxB = idxA + 64;
  const bool hi = (lg >= 2);

  for (int ch = 0; ch < 8; ++ch){
    #pragma unroll
    for (int sub = 0; sub < 2; ++sub){
      const int tloc = ch*256 + w*64 + sub*32;
      const unsigned short* kp = kb2 + (size_t)tloc*HD;
      short8 k0A = *reinterpret_cast<const short8*>(kp);
      short8 k1A = *reinterpret_cast<const short8*>(kp + 32);
      short8 k0B = *reinterpret_cast<const short8*>(kp + 16*HD);
      short8 k1B = *reinterpret_cast<const short8*>(kp + 16*HD + 32);
      short8 bv[4];
      #pragma unroll
      for (int dt = 0; dt < 4; ++dt)
        bv[dt] = *reinterpret_cast<const short8*>(vb2 + (size_t)(dt*16)*SS + tloc);

      #pragma unroll
      for (int qs = 0; qs < 2; ++qs){
        float4v pA = {};
        pA = __builtin_amdgcn_mfma_f32_16x16x32_bf16(k0A, aq[qs][0], pA, 0, 0, 0);
        pA = __builtin_amdgcn_mfma_f32_16x16x32_bf16(k1A, aq[qs][1], pA, 0, 0, 0);
        float4v pB = {};
        pB = __builtin_amdgcn_mfma_f32_16x16x32_bf16(k0B, aq[qs][0], pB, 0, 0, 0);
        pB = __builtin_amdgcn_mfma_f32_16x16x32_bf16(k1B, aq[qs][1], pB, 0, 0, 0);
        float4v eA, eB;
        eA.x = exp2f(fmaf(pA[0], scale2, cc[qs]));
        eA.y = exp2f(fmaf(pA[1], scale2, cc[qs]));
        eA.z = exp2f(fmaf(pA[2], scale2, cc[qs]));
        eA.w = exp2f(fmaf(pA[3], scale2, cc[qs]));
        eB.x = exp2f(fmaf(pB[0], scale2, cc[qs]));
        eB.y = exp2f(fmaf(pB[1], scale2, cc[qs]));
        eB.z = exp2f(fmaf(pB[2], scale2, cc[qs]));
        eB.w = exp2f(fmaf(pB[3], scale2, cc[qs]));

        // stage into shared chunk tile (chunk-relative cols)
        const int cw = w*64 + sub*32;
        *reinterpret_cast<float4v*>(&smem[(qs*16 + lr)*260 + cw + lg*4]) = eA;
        *reinterpret_cast<float4v*>(&smem[(qs*16 + lr)*260 + cw + 16 + lg*4]) = eB;

        // PV exchange (register path, independent of staging)
        const int w0A = ((int)f2bf(eA.y) << 16) | (int)f2bf(eA.x);
        const int w1A = ((int)f2bf(eA.w) << 16) | (int)f2bf(eA.z);
        const int w0B = ((int)f2bf(eB.y) << 16) | (int)f2bf(eB.x);
        const int w1B = ((int)f2bf(eB.w) << 16) | (int)f2bf(eB.z);
        const int a0 = __builtin_amdgcn_ds_bpermute(idxA, w0A);
        const int b0 = __builtin_amdgcn_ds_bpermute(idxA, w0B);
        const int a1 = __builtin_amdgcn_ds_bpermute(idxA, w1A);
        const int b1 = __builtin_amdgcn_ds_bpermute(idxA, w1B);
        const int a2 = __builtin_amdgcn_ds_bpermute(idxB, w0A);
        const int b2 = __builtin_amdgcn_ds_bpermute(idxB, w0B);
        const int a3 = __builtin_amdgcn_ds_bpermute(idxB, w1A);
        const int b3 = __builtin_amdgcn_ds_bpermute(idxB, w1B);
        int4v words;
        words.x = hi ? b0 : a0;
        words.y = hi ? b1 : a1;
        words.z = hi ? b2 : a2;
        words.w = hi ? b3 : a3;
        const short8 pa = __builtin_bit_cast(short8, words);
        #pragma unroll
        for (int dt = 0; dt < 4; ++dt)
          oacc[qs][dt] = __builtin_amdgcn_mfma_f32_16x16x32_bf16(pa, bv[dt], oacc[qs][dt], 0, 0, 0);
      }
    }
    __syncthreads();   // stage complete (cross-wave fence)
    // fill-style stores: wave w, iter i -> row i*4+w, 64 lanes = 1KB contig
    #pragma unroll
    for (int i = 0; i < 8; ++i){
      const int row = i*4 + w;
      const float4v val = *reinterpret_cast<const float4v*>(&smem[row*260 + l*4]);
      __builtin_nontemporal_store(val,
        reinterpret_cast<float4v*>(gwb + (size_t)row*SS + ch*256 + l*4));
    }
    __syncthreads();   // reads done before next chunk overwrites stage
  }

  // ---- cross-wave O reduce in two 16-col chunks (reuses smem as ored)
  float* ored = smem;   // [4][32*32]
  #pragma unroll
  for (int c = 0; c < 2; ++c){
    if (c) __syncthreads();
    #pragma unroll
    for (int qs = 0; qs < 2; ++qs)
      #pragma unroll
      for (int dl = 0; dl < 2; ++dl)
        #pragma unroll
        for (int r = 0; r < 4; ++r)
          ored[w*1024 + (qs*16 + lg*4 + r)*32 + dl*16 + lr] = oacc[qs][c*2 + dl][r];
    __syncthreads();
    const int row = t >> 3, c4 = (t & 7);
    const float4v* o0 = reinterpret_cast<const float4v*>(smem);
    const int fi = row*8 + c4;
    float4v s = o0[fi];
    s += o0[fi + 256];
    s += o0[fi + 512];
    s += o0[fi + 768];
    ushort4v o4;
    o4.x = f2bf(s.x); o4.y = f2bf(s.y); o4.z = f2bf(s.z); o4.w = f2bf(s.w);
    *reinterpret_cast<ushort4v*>(AO + ((size_t)b*SS + q0 + row)*DM + h*HD + c*32 + c4*4) = o4;
  }
}

extern "C" void kernel_launch(void* const* d_in, const int* in_sizes, int n_in,
                              void* d_out, int out_size, void* d_ws, size_t ws_size,
                              hipStream_t stream){
  const float* q      = (const float*)d_in[0];
  const float* k      = (const float*)d_in[1];
  const float* v      = (const float*)d_in[2];
  const float* phase  = (const float*)d_in[3];
  const float* Wq     = (const float*)d_in[4];
  const float* bq     = (const float*)d_in[5];
  const float* Wk     = (const float*)d_in[6];
  const float* bk     = (const float*)d_in[7];
  const float* Wv     = (const float*)d_in[8];
  const float* bv     = (const float*)d_in[9];
  const float* Wo     = (const float*)d_in[10];
  const float* bo     = (const float*)d_in[11];
  const float* pc     = (const float*)d_in[12];
  const float* ascale = (const float*)d_in[13];
  const float* stab   = (const float*)d_in[14];

  unsigned short* Xq  = (unsigned short*)d_ws;
  unsigned short* Xk  = Xq  + 4194304;
  unsigned short* Xv  = Xk  + 4194304;
  unsigned short* Wqb = Xv  + 4194304;
  unsigned short* Wkb = Wqb + 1048576;
  unsigned short* Wvb = Wkb + 1048576;
  unsigned short* Wob = Wvb + 1048576;
  unsigned short* Qh  = Wob + 1048576;
  unsigned short* Kh  = Qh  + 4194304;
  unsigned short* Vt  = Kh  + 4194304;
  unsigned short* AO  = Vt  + 4194304;   // total 64 MB of ws

  float* out0  = (float*)d_out;
  float* attnW = out0 + (size_t)MTOT*DM;

  cvt3_kernel<<<dim3(512,1,3), 256, 0, stream>>>(q, k, v, Xq, Xk, Xv, MTOT*DM);
  cvt4_kernel<<<dim3(128,1,4), 256, 0, stream>>>(Wq, Wk, Wv, Wo, Wqb, Wkb, Wvb, Wob, DM*DM);

  gemm_proj<<<dim3(DM/128, MTOT/128, 3), 256, 0, stream>>>(
      Xq, Xk, Xv, Wqb, Wkb, Wvb, bq, bk, bv, Qh, Kh, Vt);

  attn_kernel<<<dim3(32, SS/32, 1), 256, 0, stream>>>(Qh, Kh, Vt, AO, attnW,
                                                      phase, pc, ascale);

  gemm_out<<<dim3(DM/128, MTOT/128, 1), 256, 0, stream>>>(AO, Wob, bo, out0, stab);
}